// Round 8
// baseline (178.789 us; speedup 1.0000x reference)
//
#include <hip/hip_runtime.h>

// DynamicMaskHead, two-kernel split, MFMA MLP:
//   A) mlp_mfma_kernel: per-instance 10->8->8->1 MLP via v_mfma_f32_16x16x16_f16
//      - per 16-px tile: 3 MFMAs; weights live in A-fragments (6 VGPRs, loaded once)
//      - C/D layout (col=lane&15,row=(lane>>4)*4+reg) == B layout (n,k) for 16x16
//        shapes -> relu + f32->f16 cvt between layers is in-register, no permutes
//      - bias as K-row: X[10]=1.0, A[m][10]=bias[m]
//   B) upsample_kernel: aligned_bilinear x2 from d_ws -> out (unchanged, r5)

#define HI 128
#define WI 192
#define HW_ (HI * WI)        // 24576
#define NP 169
#define NOUT_W 384
#define NOUT_H 256
#define LOGITS_BYTES (256u * (unsigned)HW_ * 4u)   // 25,165,824

typedef _Float16 h4 __attribute__((ext_vector_type(4)));
typedef float    f4 __attribute__((ext_vector_type(4)));

// ---------------- Kernel A: MFMA MLP -> logits[256][128*192] ----------------
// 6144 blocks = 256 instances x 24 chunks (1024 px); 256 thr = 4 waves;
// wave handles 256 px = 16 tiles of 16 px, in 4 store-groups of 64 px.
__global__ __launch_bounds__(256, 4) void mlp_mfma_kernel(
    const float* __restrict__ feats,    // [2,8,128,192]
    const float* __restrict__ params,   // [256,169]
    const float* __restrict__ locs,     // [256,2]
    const float* __restrict__ soi,      // [5]
    const int*   __restrict__ im_inds,  // [256]
    const int*   __restrict__ lvls,     // [256]
    float*       __restrict__ logits)   // [256,128*192]
{
    const int b      = blockIdx.x;
    const int n_inst = b / 24;
    const int chunk  = b - n_inst * 24;
    const int t      = threadIdx.x;
    const int wave   = t >> 6;
    const int lane   = t & 63;
    const int g      = lane >> 4;    // k-group: k = 4g+j
    const int nn     = lane & 15;    // pixel-in-tile for B/C; row m for A

    const int   im    = im_inds[n_inst];
    const float s     = soi[lvls[n_inst]];
    const float inv_s = 1.0f / s;
    const float* __restrict__ P = params + n_inst * NP;
    const float* __restrict__ F = feats + im * (8 * HW_);
    const float step = 8.0f * inv_s;
    const float ax   = (locs[2 * n_inst + 0] - 4.0f) * inv_s;
    const float ay   = (locs[2 * n_inst + 1] - 4.0f) * inv_s;

    // ---- A fragments (loaded once; m = nn, k = 4g+j) ----
    // layer0: A0[m][k] = w0[m][k] (k<10), b0[m] (k==10), 0 else   (m<8)
    // layer1: A1[m][k] = w1[m][k] (k<8),  b1[m] (k==8),  0 else   (m<8)
    // layer2: A2[0][k] = w2[k]    (k<8),  b2    (k==8),  0 else   (m==0)
    h4 A0, A1, A2;
    #pragma unroll
    for (int j = 0; j < 4; ++j) {
        const int k = 4 * g + j;
        float w0 = 0.0f, w1 = 0.0f, w2 = 0.0f;
        if (nn < 8) {
            if (k < 10)      w0 = P[nn * 10 + k];
            else if (k == 10) w0 = P[152 + nn];
            if (k < 8)       w1 = P[80 + nn * 8 + k];
            else if (k == 8)  w1 = P[160 + nn];
        }
        if (nn == 0) {
            if (k < 8)       w2 = P[144 + k];
            else if (k == 8)  w2 = P[168];
        }
        A0[j] = (_Float16)w0; A1[j] = (_Float16)w1; A2[j] = (_Float16)w2;
    }

    const int px_wave = chunk * 1024 + wave * 256;
    const f4 zero = {0.0f, 0.0f, 0.0f, 0.0f};

    for (int grp = 0; grp < 4; ++grp) {
        float lgt[4];
        #pragma unroll
        for (int tt = 0; tt < 4; ++tt) {
            const int px0 = px_wave + grp * 64 + tt * 16;  // tile base (row-aligned: 192%16==0)
            const int py  = px0 / WI;
            const int pxx = px0 - py * WI;
            const float ry = ay - (float)py * step;
            const float rx = ax - (float)(pxx + nn) * step;
            const int   px = px0 + nn;

            // B fragment: X[k][n]; k=0 rx, k=1 ry, k=2..9 feats, k=10 bias=1, else 0
            h4 B;
            #pragma unroll
            for (int j = 0; j < 4; ++j) {
                const int k = 4 * g + j;
                const int c = min(max(k - 2, 0), 7);      // clamped channel
                float v = F[c * HW_ + px];                // always load (L2-hot)
                v = (k == 0)  ? rx   : v;
                v = (k == 1)  ? ry   : v;
                v = (k == 10) ? 1.0f : v;
                v = (k > 10)  ? 0.0f : v;
                B[j] = (_Float16)v;
            }

            f4 C0 = __builtin_amdgcn_mfma_f32_16x16x16f16(A0, B, zero, 0, 0, 0);

            // repack: B1[k][n] = relu(h0[k][n]) (k<8), 1.0 (k==8), 0 else
            h4 B1;
            #pragma unroll
            for (int j = 0; j < 4; ++j) {
                float r = fmaxf(C0[j], 0.0f);             // g>=2 rows are 0 anyway
                r = (g == 2) ? ((j == 0) ? 1.0f : 0.0f) : r;
                B1[j] = (_Float16)r;
            }
            f4 C1 = __builtin_amdgcn_mfma_f32_16x16x16f16(A1, B1, zero, 0, 0, 0);

            h4 B2;
            #pragma unroll
            for (int j = 0; j < 4; ++j) {
                float r = fmaxf(C1[j], 0.0f);
                r = (g == 2) ? ((j == 0) ? 1.0f : 0.0f) : r;
                B2[j] = (_Float16)r;
            }
            f4 C2 = __builtin_amdgcn_mfma_f32_16x16x16f16(A2, B2, zero, 0, 0, 0);
            lgt[tt] = C2[0];   // logit(px0+nn) valid in lanes g==0
        }
        // collect 4 tiles -> full-wave coalesced store of 64 px
        const float v0 = __shfl(lgt[0], nn, 64);
        const float v1 = __shfl(lgt[1], nn, 64);
        const float v2 = __shfl(lgt[2], nn, 64);
        const float v3 = __shfl(lgt[3], nn, 64);
        float outv = (g == 0) ? v0 : (g == 1) ? v1 : (g == 2) ? v2 : v3;
        logits[n_inst * HW_ + px_wave + grp * 64 + lane] = outv;
    }
}

// ---------------- Kernel B: aligned_bilinear x2 from logits ----------------
// out[y][x] = interp[max(y-1,0)][max(x-1,0)]
//   rows: ry0=iy2>>1, fy=iy2&1 -> row ry0 or avg(ry0, min(ry0+1,127))
//   cols: out[2m]=0.5*(v[m-1]+v[m]) (clamp m-1>=0), out[2m+1]=v[m]
__global__ __launch_bounds__(256, 4) void upsample_kernel(
    const float* __restrict__ logits,   // [256,128*192]
    float*       __restrict__ out)      // [256,1,256,384]
{
    const int b  = blockIdx.x;
    const int n  = b >> 2;
    const int qq = b & 3;
    const int t  = threadIdx.x;
    const int Y0 = qq << 6;

    const float* __restrict__ Lg = logits + n * HW_;
    float* __restrict__ O = out + n * (NOUT_H * NOUT_W) + Y0 * NOUT_W;

    for (int g = t; g < 3072; g += 256) {     // 64 rows * 48 groups
        const int yq = g / 48;
        const int c  = g - yq * 48;
        const int y  = Y0 + yq;
        const int iy2 = (y == 0) ? 0 : (y - 1);
        const int ry0 = iy2 >> 1;
        const int fy  = iy2 & 1;
        const int j0  = c << 2;
        const int jm  = (c == 0) ? 0 : (j0 - 1);

        const float* row0 = Lg + ry0 * WI;
        float4 v  = *reinterpret_cast<const float4*>(row0 + j0);
        float  vm = row0[jm];
        if (fy) {
            const float* row1 = Lg + min(ry0 + 1, HI - 1) * WI;
            const float4 w  = *reinterpret_cast<const float4*>(row1 + j0);
            const float  wm = row1[jm];
            v.x = 0.5f * (v.x + w.x); v.y = 0.5f * (v.y + w.y);
            v.z = 0.5f * (v.z + w.z); v.w = 0.5f * (v.w + w.w);
            vm  = 0.5f * (vm + wm);
        }
        float4 r0, r1;
        r0.x = 0.5f * (vm + v.x);  r0.y = v.x;
        r0.z = 0.5f * (v.x + v.y); r0.w = v.y;
        r1.x = 0.5f * (v.y + v.z); r1.y = v.z;
        r1.z = 0.5f * (v.z + v.w); r1.w = v.w;

        float* o8 = O + (g << 3);
        *reinterpret_cast<float4*>(o8)     = r0;
        *reinterpret_cast<float4*>(o8 + 4) = r1;
    }
}

// ---------------- Fallback: fused single kernel (round-4 version) ----------
__global__ __launch_bounds__(512, 4) void dynmask_fused(
    const float* __restrict__ feats, const float* __restrict__ params,
    const float* __restrict__ locs, const float* __restrict__ soi,
    const int* __restrict__ im_inds, const int* __restrict__ lvls,
    float* __restrict__ out)
{
    __shared__ __align__(16) float L[33 * WI];
    const int b  = blockIdx.x;
    const int n  = b >> 2;
    const int qq = b & 3;
    const int t  = threadIdx.x;
    const int R0 = (qq == 0) ? 0 : (32 * qq - 1);

    const int   im    = im_inds[n];
    const float s     = soi[lvls[n]];
    const float inv_s = 1.0f / s;
    const float* __restrict__ P = params + n * NP;
    const float* __restrict__ F = feats + im * (8 * HW_);
    const float step = 8.0f * inv_s;
    const float ax   = (locs[2 * n + 0] - 4.0f) * inv_s;
    const float ay   = (locs[2 * n + 1] - 4.0f) * inv_s;

    for (int idx = t; idx < 3168; idx += 512) {
        const int r   = idx / 96;
        const int c2  = idx - r * 96;
        const int py  = R0 + r;
        const int px0 = c2 * 2;
        const int gp  = py * WI + px0;
        const float ry  = ay - (float)py * step;
        const float rx0 = ax - (float)px0 * step;
        const float rx[2] = {rx0, rx0 - step};

        float fv[8][2];
        #pragma unroll
        for (int k = 0; k < 8; ++k) {
            const float2 v = *reinterpret_cast<const float2*>(F + k * HW_ + gp);
            fv[k][0] = v.x; fv[k][1] = v.y;
        }
        float h0[8][2];
        #pragma unroll
        for (int o = 0; o < 8; ++o) {
            const float base = fmaf(P[o * 10 + 1], ry, P[152 + o]);
            #pragma unroll
            for (int j = 0; j < 2; ++j) h0[o][j] = fmaf(P[o * 10 + 0], rx[j], base);
            #pragma unroll
            for (int k = 0; k < 8; ++k)
                #pragma unroll
                for (int j = 0; j < 2; ++j) h0[o][j] = fmaf(P[o * 10 + 2 + k], fv[k][j], h0[o][j]);
            #pragma unroll
            for (int j = 0; j < 2; ++j) h0[o][j] = fmaxf(h0[o][j], 0.0f);
        }
        float h1[8][2];
        #pragma unroll
        for (int o = 0; o < 8; ++o) {
            #pragma unroll
            for (int j = 0; j < 2; ++j) h1[o][j] = P[160 + o];
            #pragma unroll
            for (int i = 0; i < 8; ++i)
                #pragma unroll
                for (int j = 0; j < 2; ++j) h1[o][j] = fmaf(P[80 + o * 8 + i], h0[i][j], h1[o][j]);
            #pragma unroll
            for (int j = 0; j < 2; ++j) h1[o][j] = fmaxf(h1[o][j], 0.0f);
        }
        float lg[2] = {P[168], P[168]};
        #pragma unroll
        for (int i = 0; i < 8; ++i)
            #pragma unroll
            for (int j = 0; j < 2; ++j) lg[j] = fmaf(P[144 + i], h1[i][j], lg[j]);
        L[idx * 2] = lg[0]; L[idx * 2 + 1] = lg[1];
    }
    __syncthreads();

    const int Y0 = qq << 6;
    float* __restrict__ O = out + n * (NOUT_H * NOUT_W) + Y0 * NOUT_W;
    for (int g = t; g < 3072; g += 512) {
        const int yq = g / 48;
        const int c  = g - yq * 48;
        const int y  = Y0 + yq;
        const int iy2 = (y == 0) ? 0 : (y - 1);
        const int ry0 = iy2 >> 1;
        const int fy  = iy2 & 1;
        const int lr0 = ry0 - R0;
        const int j0  = c << 2;
        const int jm  = (c == 0) ? 0 : (j0 - 1);
        const float* row0 = &L[lr0 * WI];
        float4 v  = *reinterpret_cast<const float4*>(row0 + j0);
        float  vm = row0[jm];
        if (fy) {
            const float* row1 = &L[(min(ry0 + 1, HI - 1) - R0) * WI];
            const float4 w  = *reinterpret_cast<const float4*>(row1 + j0);
            const float  wm = row1[jm];
            v.x = 0.5f * (v.x + w.x); v.y = 0.5f * (v.y + w.y);
            v.z = 0.5f * (v.z + w.z); v.w = 0.5f * (v.w + w.w);
            vm  = 0.5f * (vm + wm);
        }
        float4 r0, r1;
        r0.x = 0.5f * (vm + v.x);  r0.y = v.x;
        r0.z = 0.5f * (v.x + v.y); r0.w = v.y;
        r1.x = 0.5f * (v.y + v.z); r1.y = v.z;
        r1.z = 0.5f * (v.z + v.w); r1.w = v.w;
        float* o8 = O + (g << 3);
        *reinterpret_cast<float4*>(o8)     = r0;
        *reinterpret_cast<float4*>(o8 + 4) = r1;
    }
}

extern "C" void kernel_launch(void* const* d_in, const int* in_sizes, int n_in,
                              void* d_out, int out_size, void* d_ws, size_t ws_size,
                              hipStream_t stream) {
    const float* feats   = (const float*)d_in[0];
    const float* params  = (const float*)d_in[1];
    const float* locs    = (const float*)d_in[2];
    const float* soi     = (const float*)d_in[3];
    const int*   im_inds = (const int*)d_in[4];
    const int*   lvls    = (const int*)d_in[5];
    float*       out     = (float*)d_out;

    if (ws_size >= (size_t)LOGITS_BYTES) {
        float* logits = (float*)d_ws;
        mlp_mfma_kernel<<<6144, 256, 0, stream>>>(feats, params, locs, soi, im_inds, lvls, logits);
        upsample_kernel<<<1024, 256, 0, stream>>>(logits, out);
    } else {
        dynmask_fused<<<1024, 512, 0, stream>>>(feats, params, locs, soi, im_inds, lvls, out);
    }
}